// Round 1
// baseline (573.563 us; speedup 1.0000x reference)
//
#include <hip/hip_runtime.h>
#include <stdint.h>

#define N_NODES 100000
#define N_EDGES 3200000
#define DIM 128
#define NPAD 100032   // 1563 * 64
#define CAP 128

typedef short short8 __attribute__((ext_vector_type(8)));
typedef float f32x4 __attribute__((ext_vector_type(4)));

__device__ __forceinline__ short f2bf(float x) {
    uint32_t u = __builtin_bit_cast(uint32_t, x);
    u += 0x7fffu + ((u >> 16) & 1u);   // round-to-nearest-even
    return (short)(u >> 16);
}
__device__ __forceinline__ float bflo(uint32_t p) {  // low half (element 2k)
    return __builtin_bit_cast(float, p << 16);
}
__device__ __forceinline__ float bfhi(uint32_t p) {  // high half (element 2k+1)
    return __builtin_bit_cast(float, p & 0xffff0000u);
}

// ---- K1: feat f32 -> bf16 (packed), 4 elems/thread ----------------------
__global__ __launch_bounds__(256) void cast_kernel(const float* __restrict__ feat,
                                                   uint32_t* __restrict__ featbf) {
    int i = blockIdx.x * 256 + threadIdx.x;          // one float4 per thread
    float4 f = ((const float4*)feat)[i];
    uint32_t lo = (uint32_t)(uint16_t)f2bf(f.x) | ((uint32_t)(uint16_t)f2bf(f.y) << 16);
    uint32_t hi = (uint32_t)(uint16_t)f2bf(f.z) | ((uint32_t)(uint16_t)f2bf(f.w) << 16);
    featbf[2 * i]     = lo;
    featbf[2 * i + 1] = hi;
}

// ---- K2: W1,W2 f32 [k][n] -> bf16 transposed [n][k] ---------------------
__global__ __launch_bounds__(256) void wtrans_kernel(const float* __restrict__ w1,
                                                     const float* __restrict__ w2,
                                                     short* __restrict__ w1t,
                                                     short* __restrict__ w2t) {
    int i = blockIdx.x * 256 + threadIdx.x;          // grid = 64 blocks -> 16384
    int k = i >> 7, n = i & 127;
    w1t[n * DIM + k] = f2bf(w1[i]);
    w2t[n * DIM + k] = f2bf(w2[i]);
}

// ---- K3: bucket fill ----------------------------------------------------
__global__ __launch_bounds__(256) void fill_kernel(const int* __restrict__ src,
                                                   const int* __restrict__ dst,
                                                   int* __restrict__ cnt,
                                                   int* __restrict__ bucket) {
    int e = blockIdx.x * 256 + threadIdx.x;          // grid covers exactly N_EDGES
    int v = dst[e];
    int slot = atomicAdd(&cnt[v], 1);
    if (slot < CAP) bucket[v * CAP + slot] = src[e];
}

// ---- K4: wave-per-node gather-sum + (1+eps)*feat, write h_pre bf16 ------
__global__ __launch_bounds__(256) void gather_kernel(const float* __restrict__ feat,
                                                     const uint32_t* __restrict__ featbf,
                                                     const int* __restrict__ bucket,
                                                     const int* __restrict__ cnt,
                                                     const float* __restrict__ eps,
                                                     uint32_t* __restrict__ hbf) {
    int wid = blockIdx.x * 4 + (threadIdx.x >> 6);   // node id, grid*4 == NPAD
    int lane = threadIdx.x & 63;
    if (wid >= N_NODES) {                            // pad rows -> zero
        if (wid < NPAD) hbf[wid * 64 + lane] = 0;
        return;
    }
    float e1 = 1.0f + eps[0];
    float2 f = *(const float2*)&feat[wid * DIM + lane * 2];
    float a0 = e1 * f.x;
    float a1 = e1 * f.y;
    int c = min(cnt[wid], CAP);
    int b0 = (lane < c)      ? bucket[wid * CAP + lane]      : 0;
    int b1 = (lane + 64 < c) ? bucket[wid * CAP + 64 + lane] : 0;
    for (int i = 0; i < c; i++) {
        int u = __shfl((i < 64) ? b0 : b1, i & 63);
        uint32_t p = featbf[u * 64 + lane];          // 2 bf16, coalesced 256B/row
        a0 += bflo(p);
        a1 += bfhi(p);
    }
    uint32_t r = (uint32_t)(uint16_t)f2bf(a0) | ((uint32_t)(uint16_t)f2bf(a1) << 16);
    hbf[wid * 64 + lane] = r;
}

// ---- K5: fused 2-layer MLP via bf16 MFMA 16x16x32 -----------------------
// h1 = relu(h @ W1 + b1); out = h1 @ W2 + b2
__global__ __launch_bounds__(256) void mlp_kernel(const short* __restrict__ hbf,
                                                  const short* __restrict__ w1t,
                                                  const short* __restrict__ w2t,
                                                  const float* __restrict__ b1,
                                                  const float* __restrict__ b2,
                                                  float* __restrict__ out) {
    __shared__ __align__(16) short h1s[4][16 * 136];  // per-wave staging, +8 pad
    const int wave = threadIdx.x >> 6;
    const int lane = threadIdx.x & 63;
    const int l15 = lane & 15;
    const int quad = lane >> 4;

    float b1v[8], b2v[8];
#pragma unroll
    for (int n = 0; n < 8; n++) {
        b1v[n] = b1[n * 16 + l15];
        b2v[n] = b2[n * 16 + l15];
    }

    const int ntiles = NPAD / 64;                    // 1563
    for (int tile = blockIdx.x; tile < ntiles; tile += gridDim.x) {
        int row0 = tile * 64 + wave * 16;
        // ---- layer 1 ----
        f32x4 acc[8];
#pragma unroll
        for (int n = 0; n < 8; n++) acc[n] = (f32x4){0.f, 0.f, 0.f, 0.f};
#pragma unroll
        for (int kb = 0; kb < DIM; kb += 32) {
            short8 a = *(const short8*)&hbf[(row0 + l15) * DIM + kb + quad * 8];
#pragma unroll
            for (int n = 0; n < 8; n++) {
                short8 b = *(const short8*)&w1t[(n * 16 + l15) * DIM + kb + quad * 8];
                acc[n] = __builtin_amdgcn_mfma_f32_16x16x32_bf16(a, b, acc[n], 0, 0, 0);
            }
        }
        // epilogue 1: bias + relu -> bf16 -> LDS (A-operand layout for layer 2)
#pragma unroll
        for (int n = 0; n < 8; n++) {
#pragma unroll
            for (int r = 0; r < 4; r++) {
                float v = acc[n][r] + b1v[n];
                v = v > 0.f ? v : 0.f;
                h1s[wave][(quad * 4 + r) * 136 + n * 16 + l15] = f2bf(v);
            }
        }
        __syncthreads();
        // ---- layer 2 ----
        f32x4 acc2[8];
#pragma unroll
        for (int n = 0; n < 8; n++) acc2[n] = (f32x4){0.f, 0.f, 0.f, 0.f};
#pragma unroll
        for (int kb = 0; kb < DIM; kb += 32) {
            short8 a2 = *(const short8*)&h1s[wave][l15 * 136 + kb + quad * 8];
#pragma unroll
            for (int n = 0; n < 8; n++) {
                short8 b = *(const short8*)&w2t[(n * 16 + l15) * DIM + kb + quad * 8];
                acc2[n] = __builtin_amdgcn_mfma_f32_16x16x32_bf16(a2, b, acc2[n], 0, 0, 0);
            }
        }
        // epilogue 2: bias -> global f32
#pragma unroll
        for (int n = 0; n < 8; n++) {
#pragma unroll
            for (int r = 0; r < 4; r++) {
                int row = row0 + quad * 4 + r;
                if (row < N_NODES)
                    out[row * DIM + n * 16 + l15] = acc2[n][r] + b2v[n];
            }
        }
        __syncthreads();
    }
}

extern "C" void kernel_launch(void* const* d_in, const int* in_sizes, int n_in,
                              void* d_out, int out_size, void* d_ws, size_t ws_size,
                              hipStream_t stream) {
    const float* feat = (const float*)d_in[0];
    const int* src    = (const int*)d_in[1];
    const int* dst    = (const int*)d_in[2];
    const float* eps  = (const float*)d_in[3];
    const float* W1   = (const float*)d_in[4];
    const float* b1   = (const float*)d_in[5];
    const float* W2   = (const float*)d_in[6];
    const float* b2   = (const float*)d_in[7];
    float* out = (float*)d_out;

    // workspace layout (all offsets 16B-aligned)
    char* ws = (char*)d_ws;
    int*      cnt    = (int*)ws;                                  // 400,128 B
    int*      bucket = (int*)(ws + 400128);                       // 51,200,000 B
    uint32_t* featbf = (uint32_t*)(ws + 400128 + 51200000);       // 25,600,000 B
    uint32_t* hbf    = (uint32_t*)(ws + 400128 + 51200000 + 25600000);      // 25,608,192 B
    short*    w1t    = (short*)(ws + 400128 + 51200000 + 25600000 + 25608192); // 32,768 B
    short*    w2t    = (short*)(ws + 400128 + 51200000 + 25600000 + 25608192 + 32768);

    hipMemsetAsync(cnt, 0, NPAD * sizeof(int), stream);

    cast_kernel<<<(N_NODES * DIM / 4) / 256, 256, 0, stream>>>(feat, featbf);
    wtrans_kernel<<<64, 256, 0, stream>>>(W1, W2, w1t, w2t);
    fill_kernel<<<N_EDGES / 256, 256, 0, stream>>>(src, dst, cnt, bucket);
    gather_kernel<<<NPAD / 4, 256, 0, stream>>>(feat, featbf, bucket, cnt, eps,
                                                (uint32_t*)hbf);
    mlp_kernel<<<1024, 256, 0, stream>>>((const short*)hbf, w1t, w2t, b1, b2, out);
}

// Round 2
// 409.500 us; speedup vs baseline: 1.4006x; 1.4006x over previous
//
#include <hip/hip_runtime.h>
#include <stdint.h>

#define N_NODES 100000
#define N_EDGES 3200000
#define DIM 128
#define NPAD 100032   // 1563 * 64
#define NBINS 391     // ceil(100000 / 256) -- 256 nodes per bin
#define BCAP 10240    // bin capacity; mean 8192, sigma ~90 -> 22 sigma slack
#define EPB 4096      // edges per bin_kernel block (16/thread)

typedef short short8 __attribute__((ext_vector_type(8)));
typedef float f32x4 __attribute__((ext_vector_type(4)));

__device__ __forceinline__ short f2bf(float x) {
    uint32_t u = __builtin_bit_cast(uint32_t, x);
    u += 0x7fffu + ((u >> 16) & 1u);   // round-to-nearest-even
    return (short)(u >> 16);
}
__device__ __forceinline__ float bflo(uint32_t p) {
    return __builtin_bit_cast(float, p << 16);
}
__device__ __forceinline__ float bfhi(uint32_t p) {
    return __builtin_bit_cast(float, p & 0xffff0000u);
}

// ---- K1: feat f32 -> bf16 (packed) --------------------------------------
__global__ __launch_bounds__(256) void cast_kernel(const float* __restrict__ feat,
                                                   uint32_t* __restrict__ featbf) {
    int i = blockIdx.x * 256 + threadIdx.x;
    float4 f = ((const float4*)feat)[i];
    featbf[2 * i]     = (uint32_t)(uint16_t)f2bf(f.x) | ((uint32_t)(uint16_t)f2bf(f.y) << 16);
    featbf[2 * i + 1] = (uint32_t)(uint16_t)f2bf(f.z) | ((uint32_t)(uint16_t)f2bf(f.w) << 16);
}

// ---- K2: W1,W2 f32 [k][n] -> bf16 transposed [n][k] ---------------------
__global__ __launch_bounds__(256) void wtrans_kernel(const float* __restrict__ w1,
                                                     const float* __restrict__ w2,
                                                     short* __restrict__ w1t,
                                                     short* __restrict__ w2t) {
    int i = blockIdx.x * 256 + threadIdx.x;
    int k = i >> 7, n = i & 127;
    w1t[n * DIM + k] = f2bf(w1[i]);
    w2t[n * DIM + k] = f2bf(w2[i]);
}

// ---- K3a: bin edges by dst>>8, block-aggregated reservation -------------
__global__ __launch_bounds__(256) void bin_kernel(const int* __restrict__ src,
                                                  const int* __restrict__ dst,
                                                  int* __restrict__ bincnt,
                                                  uint64_t* __restrict__ binpair) {
    __shared__ int hist[NBINS];
    __shared__ int base[NBINS];
    int t = threadIdx.x;
    for (int i = t; i < NBINS; i += 256) hist[i] = 0;
    __syncthreads();
    int e0 = blockIdx.x * EPB;
    int n = min(EPB, N_EDGES - e0);
    int d[16];
#pragma unroll
    for (int i = 0; i < 16; i++) {
        int idx = i * 256 + t;
        d[i] = (idx < n) ? dst[e0 + idx] : -1;
        if (d[i] >= 0) atomicAdd(&hist[d[i] >> 8], 1);
    }
    __syncthreads();
    for (int i = t; i < NBINS; i += 256) {
        int h = hist[i];
        base[i] = h ? atomicAdd(&bincnt[i], h) : 0;
        hist[i] = 0;
    }
    __syncthreads();
#pragma unroll
    for (int i = 0; i < 16; i++) {
        if (d[i] >= 0) {
            int b = d[i] >> 8;
            int slot = base[b] + atomicAdd(&hist[b], 1);
            if (slot < BCAP) {
                int e = e0 + i * 256 + t;
                binpair[(size_t)b * BCAP + slot] =
                    (uint64_t)(uint32_t)src[e] | ((uint64_t)(uint32_t)d[i] << 32);
            }
        }
    }
}

// ---- K3b: per-bin counting sort -> CSR ----------------------------------
__global__ __launch_bounds__(256) void csr_kernel(const int* __restrict__ bincnt,
                                                  const uint64_t* __restrict__ binpair,
                                                  int* __restrict__ rowptr,
                                                  int* __restrict__ csr) {
    __shared__ int hist[256];
    __shared__ int cursor[256];
    __shared__ int sc[256];
    __shared__ int binbase_s;
    int b = blockIdx.x;
    int t = threadIdx.x;
    // exclusive prefix over bins j < b
    int partial = 0;
    for (int j = t; j < b; j += 256) partial += min(bincnt[j], BCAP);
    sc[t] = partial;
    __syncthreads();
    for (int dd = 128; dd > 0; dd >>= 1) {
        if (t < dd) sc[t] += sc[t + dd];
        __syncthreads();
    }
    if (t == 0) binbase_s = sc[0];
    hist[t] = 0;
    __syncthreads();
    int binbase = binbase_s;
    int cntb = min(bincnt[b], BCAP);
    const uint64_t* pairs = binpair + (size_t)b * BCAP;
    // per-node histogram
    for (int i = t; i < cntb; i += 256)
        atomicAdd(&hist[(int)(pairs[i] >> 32) & 255], 1);
    __syncthreads();
    // Hillis-Steele inclusive scan of hist (256 entries)
    int val = hist[t];
    sc[t] = val;
    __syncthreads();
    for (int dd = 1; dd < 256; dd <<= 1) {
        int addv = (t >= dd) ? sc[t - dd] : 0;
        __syncthreads();
        sc[t] += addv;
        __syncthreads();
    }
    int excl = sc[t] - val;
    rowptr[(b << 8) + t] = binbase + excl;
    cursor[t] = excl;
    __syncthreads();
    // scatter srcs grouped by local node (contiguous ~33KB region per block)
    for (int i = t; i < cntb; i += 256) {
        uint64_t p = pairs[i];
        int local = (int)(p >> 32) & 255;
        int s2 = atomicAdd(&cursor[local], 1);
        csr[binbase + s2] = (int)(uint32_t)p;
    }
}

// ---- K4: wave-per-node CSR gather-sum + (1+eps)*feat, write bf16 --------
__global__ __launch_bounds__(256) void gather_kernel(const float* __restrict__ feat,
                                                     const uint32_t* __restrict__ featbf,
                                                     const int* __restrict__ rowptr,
                                                     const int* __restrict__ csr,
                                                     const float* __restrict__ eps,
                                                     uint32_t* __restrict__ hbf) {
    int wid = blockIdx.x * 4 + (threadIdx.x >> 6);
    int lane = threadIdx.x & 63;
    if (wid >= N_NODES) {
        if (wid < NPAD) hbf[wid * 64 + lane] = 0;
        return;
    }
    float e1 = 1.0f + eps[0];
    float2 f = *(const float2*)&feat[wid * DIM + lane * 2];
    float a0 = e1 * f.x;
    float a1 = e1 * f.y;
    int start = rowptr[wid], end = rowptr[wid + 1];
    const uint32_t* fb = featbf + lane;
    for (int i0 = start; i0 < end; i0 += 64) {
        int m = min(64, end - i0);
        int u = (lane < m) ? csr[i0 + lane] : 0;   // coalesced edge-list read
        int j = 0;
        for (; j + 1 < m; j += 2) {                // keep 2 row-loads in flight
            int u0 = __shfl(u, j);
            int u1 = __shfl(u, j + 1);
            uint32_t p0 = fb[u0 * 64];
            uint32_t p1 = fb[u1 * 64];
            a0 += bflo(p0); a1 += bfhi(p0);
            a0 += bflo(p1); a1 += bfhi(p1);
        }
        if (j < m) {
            uint32_t p = fb[__shfl(u, j) * 64];
            a0 += bflo(p); a1 += bfhi(p);
        }
    }
    hbf[wid * 64 + lane] =
        (uint32_t)(uint16_t)f2bf(a0) | ((uint32_t)(uint16_t)f2bf(a1) << 16);
}

// ---- K5: fused 2-layer MLP via bf16 MFMA 16x16x32 -----------------------
__global__ __launch_bounds__(256) void mlp_kernel(const short* __restrict__ hbf,
                                                  const short* __restrict__ w1t,
                                                  const short* __restrict__ w2t,
                                                  const float* __restrict__ b1,
                                                  const float* __restrict__ b2,
                                                  float* __restrict__ out) {
    __shared__ __align__(16) short h1s[4][16 * 136];
    const int wave = threadIdx.x >> 6;
    const int lane = threadIdx.x & 63;
    const int l15 = lane & 15;
    const int quad = lane >> 4;

    float b1v[8], b2v[8];
#pragma unroll
    for (int n = 0; n < 8; n++) {
        b1v[n] = b1[n * 16 + l15];
        b2v[n] = b2[n * 16 + l15];
    }

    const int ntiles = NPAD / 64;
    for (int tile = blockIdx.x; tile < ntiles; tile += gridDim.x) {
        int row0 = tile * 64 + wave * 16;
        f32x4 acc[8];
#pragma unroll
        for (int n = 0; n < 8; n++) acc[n] = (f32x4){0.f, 0.f, 0.f, 0.f};
#pragma unroll
        for (int kb = 0; kb < DIM; kb += 32) {
            short8 a = *(const short8*)&hbf[(row0 + l15) * DIM + kb + quad * 8];
#pragma unroll
            for (int n = 0; n < 8; n++) {
                short8 b = *(const short8*)&w1t[(n * 16 + l15) * DIM + kb + quad * 8];
                acc[n] = __builtin_amdgcn_mfma_f32_16x16x32_bf16(a, b, acc[n], 0, 0, 0);
            }
        }
#pragma unroll
        for (int n = 0; n < 8; n++) {
#pragma unroll
            for (int r = 0; r < 4; r++) {
                float v = acc[n][r] + b1v[n];
                v = v > 0.f ? v : 0.f;
                h1s[wave][(quad * 4 + r) * 136 + n * 16 + l15] = f2bf(v);
            }
        }
        __syncthreads();
        f32x4 acc2[8];
#pragma unroll
        for (int n = 0; n < 8; n++) acc2[n] = (f32x4){0.f, 0.f, 0.f, 0.f};
#pragma unroll
        for (int kb = 0; kb < DIM; kb += 32) {
            short8 a2 = *(const short8*)&h1s[wave][l15 * 136 + kb + quad * 8];
#pragma unroll
            for (int n = 0; n < 8; n++) {
                short8 b = *(const short8*)&w2t[(n * 16 + l15) * DIM + kb + quad * 8];
                acc2[n] = __builtin_amdgcn_mfma_f32_16x16x32_bf16(a2, b, acc2[n], 0, 0, 0);
            }
        }
#pragma unroll
        for (int n = 0; n < 8; n++) {
#pragma unroll
            for (int r = 0; r < 4; r++) {
                int row = row0 + quad * 4 + r;
                if (row < N_NODES)
                    out[row * DIM + n * 16 + l15] = acc2[n][r] + b2v[n];
            }
        }
        __syncthreads();
    }
}

extern "C" void kernel_launch(void* const* d_in, const int* in_sizes, int n_in,
                              void* d_out, int out_size, void* d_ws, size_t ws_size,
                              hipStream_t stream) {
    const float* feat = (const float*)d_in[0];
    const int* src    = (const int*)d_in[1];
    const int* dst    = (const int*)d_in[2];
    const float* eps  = (const float*)d_in[3];
    const float* W1   = (const float*)d_in[4];
    const float* b1   = (const float*)d_in[5];
    const float* W2   = (const float*)d_in[6];
    const float* b2   = (const float*)d_in[7];
    float* out = (float*)d_out;

    // workspace layout (16B-aligned offsets)
    char* ws = (char*)d_ws;
    int*      bincnt  = (int*)ws;                          // 2,048 B
    int*      rowptr  = (int*)(ws + 2048);                 // 401,408 B (100352 ints)
    int*      csr     = (int*)(ws + 403456);               // 12,800,000 B
    uint64_t* binpair = (uint64_t*)(ws + 13203456);        // 32,030,720 B
    uint32_t* featbf  = (uint32_t*)(ws + 45234176);        // 25,600,000 B
    uint32_t* hbf     = (uint32_t*)(ws + 70834176);        // 25,608,192 B
    short*    w1t     = (short*)(ws + 96442368);           // 32,768 B
    short*    w2t     = (short*)(ws + 96475136);           // 32,768 B -> total 96,507,904 B

    hipMemsetAsync(bincnt, 0, 2048, stream);

    cast_kernel<<<(N_NODES * DIM / 4) / 256, 256, 0, stream>>>(feat, featbf);
    wtrans_kernel<<<64, 256, 0, stream>>>(W1, W2, w1t, w2t);
    bin_kernel<<<(N_EDGES + EPB - 1) / EPB, 256, 0, stream>>>(src, dst, bincnt, binpair);
    csr_kernel<<<NBINS, 256, 0, stream>>>(bincnt, binpair, rowptr, csr);
    gather_kernel<<<NPAD / 4, 256, 0, stream>>>(feat, featbf, rowptr, csr, eps, hbf);
    mlp_kernel<<<1024, 256, 0, stream>>>((const short*)hbf, w1t, w2t, b1, b2, out);
}

// Round 3
// 385.537 us; speedup vs baseline: 1.4877x; 1.0622x over previous
//
#include <hip/hip_runtime.h>
#include <stdint.h>

#define N_NODES 100000
#define N_EDGES 3200000
#define DIM 128
#define NPAD 100032   // 1563 * 64
#define NBINS 391     // ceil(100000 / 256) -- 256 nodes per bin
#define BCAP 10240    // bin capacity; mean 8192
#define EPB 4096      // edges per bin_kernel block (16/thread)

typedef short short8 __attribute__((ext_vector_type(8)));
typedef float f32x4 __attribute__((ext_vector_type(4)));

__device__ __forceinline__ short f2bf(float x) {
    uint32_t u = __builtin_bit_cast(uint32_t, x);
    u += 0x7fffu + ((u >> 16) & 1u);   // round-to-nearest-even
    return (short)(u >> 16);
}
__device__ __forceinline__ float bflo(uint32_t p) {
    return __builtin_bit_cast(float, p << 16);
}
__device__ __forceinline__ float bfhi(uint32_t p) {
    return __builtin_bit_cast(float, p & 0xffff0000u);
}
__device__ __forceinline__ uint32_t pack2(float x, float y) {
    return (uint32_t)(uint16_t)f2bf(x) | ((uint32_t)(uint16_t)f2bf(y) << 16);
}

// ---- K1: feat f32 -> bf16 (packed) --------------------------------------
__global__ __launch_bounds__(256) void cast_kernel(const float* __restrict__ feat,
                                                   uint32_t* __restrict__ featbf) {
    int i = blockIdx.x * 256 + threadIdx.x;
    float4 f = ((const float4*)feat)[i];
    featbf[2 * i]     = pack2(f.x, f.y);
    featbf[2 * i + 1] = pack2(f.z, f.w);
}

// ---- K2: W1,W2 f32 [k][n] -> bf16 transposed [n][k] ---------------------
__global__ __launch_bounds__(256) void wtrans_kernel(const float* __restrict__ w1,
                                                     const float* __restrict__ w2,
                                                     short* __restrict__ w1t,
                                                     short* __restrict__ w2t) {
    int i = blockIdx.x * 256 + threadIdx.x;
    int k = i >> 7, n = i & 127;
    w1t[n * DIM + k] = f2bf(w1[i]);
    w2t[n * DIM + k] = f2bf(w2[i]);
}

// ---- K3a: bin edges by dst>>8, LDS counting-sort, coalesced write-out ---
__global__ __launch_bounds__(256) void bin_kernel(const int* __restrict__ src,
                                                  const int* __restrict__ dst,
                                                  int* __restrict__ bincnt,
                                                  uint32_t* __restrict__ binpair) {
    __shared__ int hist[512];          // padded past NBINS
    __shared__ int scanv[512];         // block-local exclusive bin offsets
    __shared__ int scan256[256];
    __shared__ int gbase[NBINS];
    __shared__ int cursor[NBINS];
    __shared__ uint32_t sorted[EPB];
    __shared__ int saddr[EPB];
    int t = threadIdx.x;
    for (int i = t; i < 512; i += 256) hist[i] = 0;
    __syncthreads();
    int e0 = blockIdx.x * EPB;
    int nn = min(EPB, N_EDGES - e0);
    int d[16];
#pragma unroll
    for (int i = 0; i < 16; i++) {
        int idx = i * 256 + t;
        d[i] = (idx < nn) ? dst[e0 + idx] : -1;
        if (d[i] >= 0) atomicAdd(&hist[d[i] >> 8], 1);
    }
    __syncthreads();
    // scan 512 bins with 256 threads (pair-sum then Hillis-Steele)
    int h0 = hist[2 * t], h1 = hist[2 * t + 1];
    scan256[t] = h0 + h1;
    __syncthreads();
    for (int dd = 1; dd < 256; dd <<= 1) {
        int v = (t >= dd) ? scan256[t - dd] : 0;
        __syncthreads();
        scan256[t] += v;
        __syncthreads();
    }
    int pairExcl = scan256[t] - (h0 + h1);
    scanv[2 * t] = pairExcl;
    scanv[2 * t + 1] = pairExcl + h0;
    for (int b = t; b < NBINS; b += 256) {
        int h = hist[b];
        gbase[b] = h ? atomicAdd(&bincnt[b], h) : 0;
        cursor[b] = 0;
    }
    __syncthreads();
    // LDS scatter into block-sorted order, remembering global address
#pragma unroll
    for (int i = 0; i < 16; i++) {
        if (d[i] >= 0) {
            int b = d[i] >> 8;
            int slot = atomicAdd(&cursor[b], 1);
            int p = scanv[b] + slot;
            int g = gbase[b] + slot;
            int e = e0 + i * 256 + t;
            sorted[p] = (uint32_t)src[e] | ((uint32_t)(d[i] & 255) << 24);
            saddr[p] = (g < BCAP) ? (b * BCAP + g) : -1;
        }
    }
    __syncthreads();
    // write-out: consecutive threads -> consecutive addresses within bin runs
    for (int i = t; i < nn; i += 256) {
        int a = saddr[i];
        if (a >= 0) binpair[a] = sorted[i];
    }
}

// ---- K3b: per-bin counting sort -> CSR ----------------------------------
__global__ __launch_bounds__(256) void csr_kernel(const int* __restrict__ bincnt,
                                                  const uint32_t* __restrict__ binpair,
                                                  int* __restrict__ rowptr,
                                                  int* __restrict__ csr) {
    __shared__ int hist[256];
    __shared__ int cursor[256];
    __shared__ int sc[256];
    __shared__ int binbase_s;
    int b = blockIdx.x;
    int t = threadIdx.x;
    int partial = 0;
    for (int j = t; j < b; j += 256) partial += min(bincnt[j], BCAP);
    sc[t] = partial;
    __syncthreads();
    for (int dd = 128; dd > 0; dd >>= 1) {
        if (t < dd) sc[t] += sc[t + dd];
        __syncthreads();
    }
    if (t == 0) binbase_s = sc[0];
    hist[t] = 0;
    __syncthreads();
    int binbase = binbase_s;
    int cntb = min(bincnt[b], BCAP);
    const uint32_t* pairs = binpair + (size_t)b * BCAP;
    for (int i = t; i < cntb; i += 256)
        atomicAdd(&hist[pairs[i] >> 24], 1);
    __syncthreads();
    int val = hist[t];
    sc[t] = val;
    __syncthreads();
    for (int dd = 1; dd < 256; dd <<= 1) {
        int addv = (t >= dd) ? sc[t - dd] : 0;
        __syncthreads();
        sc[t] += addv;
        __syncthreads();
    }
    int excl = sc[t] - val;
    rowptr[(b << 8) + t] = binbase + excl;
    cursor[t] = excl;
    __syncthreads();
    for (int i = t; i < cntb; i += 256) {
        uint32_t p = pairs[i];
        int s2 = atomicAdd(&cursor[p >> 24], 1);
        csr[binbase + s2] = (int)(p & 0x00FFFFFFu);
    }
}

// ---- K4: wave-per-node CSR gather; 2 rows per dwordx2 load, 4 in flight -
__global__ __launch_bounds__(256) void gather_kernel(const uint32_t* __restrict__ featbf,
                                                     const int* __restrict__ rowptr,
                                                     const int* __restrict__ csr,
                                                     const float* __restrict__ eps,
                                                     uint32_t* __restrict__ hbf) {
    int wid = blockIdx.x * 4 + (threadIdx.x >> 6);
    int lane = threadIdx.x & 63;
    int half = lane >> 5;       // 0: even edges, 1: odd edges
    int col = lane & 31;        // uint2 column within row
    if (wid >= N_NODES) {
        if (wid < NPAD) hbf[wid * 64 + lane] = 0;
        return;
    }
    float a0 = 0.f, a1 = 0.f, a2 = 0.f, a3 = 0.f;
    int start = rowptr[wid], end = rowptr[wid + 1];
    for (int base = start; base < end; base += 64) {
        int m = min(64, end - base);
        int u = (lane < m) ? csr[base + lane] : 0;
        int m8 = m & ~7;
        for (int j = 0; j < m8; j += 8) {     // 8 edges, 4 dwordx2 loads in flight
            int i0 = __shfl(u, j + half);
            int i1 = __shfl(u, j + 2 + half);
            int i2 = __shfl(u, j + 4 + half);
            int i3 = __shfl(u, j + 6 + half);
            uint2 q0 = *(const uint2*)&featbf[i0 * 64 + col * 2];
            uint2 q1 = *(const uint2*)&featbf[i1 * 64 + col * 2];
            uint2 q2 = *(const uint2*)&featbf[i2 * 64 + col * 2];
            uint2 q3 = *(const uint2*)&featbf[i3 * 64 + col * 2];
            a0 += bflo(q0.x); a1 += bfhi(q0.x); a2 += bflo(q0.y); a3 += bfhi(q0.y);
            a0 += bflo(q1.x); a1 += bfhi(q1.x); a2 += bflo(q1.y); a3 += bfhi(q1.y);
            a0 += bflo(q2.x); a1 += bfhi(q2.x); a2 += bflo(q2.y); a3 += bfhi(q2.y);
            a0 += bflo(q3.x); a1 += bfhi(q3.x); a2 += bflo(q3.y); a3 += bfhi(q3.y);
        }
        for (int j = m8; j < m; j += 2) {     // predicated tail (<=7 edges)
            int idx = j + half;
            int us = __shfl(u, min(idx, m - 1));
            uint2 q = *(const uint2*)&featbf[us * 64 + col * 2];
            if (idx < m) {
                a0 += bflo(q.x); a1 += bfhi(q.x);
                a2 += bflo(q.y); a3 += bfhi(q.y);
            }
        }
    }
    a0 += __shfl_xor(a0, 32);
    a1 += __shfl_xor(a1, 32);
    a2 += __shfl_xor(a2, 32);
    a3 += __shfl_xor(a3, 32);
    if (half == 0) {
        float e1 = 1.0f + eps[0];
        uint2 sf = *(const uint2*)&featbf[wid * 64 + col * 2];
        a0 += e1 * bflo(sf.x); a1 += e1 * bfhi(sf.x);
        a2 += e1 * bflo(sf.y); a3 += e1 * bfhi(sf.y);
        uint2 w;
        w.x = pack2(a0, a1);
        w.y = pack2(a2, a3);
        *(uint2*)&hbf[wid * 64 + col * 2] = w;
    }
}

// ---- K5: fused 2-layer MLP via bf16 MFMA 16x16x32 -----------------------
__global__ __launch_bounds__(256) void mlp_kernel(const short* __restrict__ hbf,
                                                  const short* __restrict__ w1t,
                                                  const short* __restrict__ w2t,
                                                  const float* __restrict__ b1,
                                                  const float* __restrict__ b2,
                                                  float* __restrict__ out) {
    __shared__ __align__(16) short h1s[4][16 * 136];
    const int wave = threadIdx.x >> 6;
    const int lane = threadIdx.x & 63;
    const int l15 = lane & 15;
    const int quad = lane >> 4;

    float b1v[8], b2v[8];
#pragma unroll
    for (int n = 0; n < 8; n++) {
        b1v[n] = b1[n * 16 + l15];
        b2v[n] = b2[n * 16 + l15];
    }

    const int ntiles = NPAD / 64;
    for (int tile = blockIdx.x; tile < ntiles; tile += gridDim.x) {
        int row0 = tile * 64 + wave * 16;
        f32x4 acc[8];
#pragma unroll
        for (int n = 0; n < 8; n++) acc[n] = (f32x4){0.f, 0.f, 0.f, 0.f};
#pragma unroll
        for (int kb = 0; kb < DIM; kb += 32) {
            short8 a = *(const short8*)&hbf[(row0 + l15) * DIM + kb + quad * 8];
#pragma unroll
            for (int n = 0; n < 8; n++) {
                short8 b = *(const short8*)&w1t[(n * 16 + l15) * DIM + kb + quad * 8];
                acc[n] = __builtin_amdgcn_mfma_f32_16x16x32_bf16(a, b, acc[n], 0, 0, 0);
            }
        }
#pragma unroll
        for (int n = 0; n < 8; n++) {
#pragma unroll
            for (int r = 0; r < 4; r++) {
                float v = acc[n][r] + b1v[n];
                v = v > 0.f ? v : 0.f;
                h1s[wave][(quad * 4 + r) * 136 + n * 16 + l15] = f2bf(v);
            }
        }
        __syncthreads();
        f32x4 acc2[8];
#pragma unroll
        for (int n = 0; n < 8; n++) acc2[n] = (f32x4){0.f, 0.f, 0.f, 0.f};
#pragma unroll
        for (int kb = 0; kb < DIM; kb += 32) {
            short8 a2 = *(const short8*)&h1s[wave][l15 * 136 + kb + quad * 8];
#pragma unroll
            for (int n = 0; n < 8; n++) {
                short8 b = *(const short8*)&w2t[(n * 16 + l15) * DIM + kb + quad * 8];
                acc2[n] = __builtin_amdgcn_mfma_f32_16x16x32_bf16(a2, b, acc2[n], 0, 0, 0);
            }
        }
#pragma unroll
        for (int n = 0; n < 8; n++) {
#pragma unroll
            for (int r = 0; r < 4; r++) {
                int row = row0 + quad * 4 + r;
                if (row < N_NODES)
                    out[row * DIM + n * 16 + l15] = acc2[n][r] + b2v[n];
            }
        }
        __syncthreads();
    }
}

extern "C" void kernel_launch(void* const* d_in, const int* in_sizes, int n_in,
                              void* d_out, int out_size, void* d_ws, size_t ws_size,
                              hipStream_t stream) {
    const float* feat = (const float*)d_in[0];
    const int* src    = (const int*)d_in[1];
    const int* dst    = (const int*)d_in[2];
    const float* eps  = (const float*)d_in[3];
    const float* W1   = (const float*)d_in[4];
    const float* b1   = (const float*)d_in[5];
    const float* W2   = (const float*)d_in[6];
    const float* b2   = (const float*)d_in[7];
    float* out = (float*)d_out;

    // workspace layout (16B-aligned offsets)
    char* ws = (char*)d_ws;
    int*      bincnt  = (int*)ws;                          //         2,048 B
    int*      rowptr  = (int*)(ws + 2048);                 //       401,408 B
    int*      csr     = (int*)(ws + 403456);               //    12,800,000 B
    uint32_t* binpair = (uint32_t*)(ws + 13203456);        //    16,015,360 B
    uint32_t* featbf  = (uint32_t*)(ws + 29218816);        //    25,600,000 B
    uint32_t* hbf     = (uint32_t*)(ws + 54818816);        //    25,608,192 B
    short*    w1t     = (short*)(ws + 80427008);           //        32,768 B
    short*    w2t     = (short*)(ws + 80459776);           // ends 80,492,544 B

    hipMemsetAsync(bincnt, 0, 2048, stream);

    cast_kernel<<<(N_NODES * DIM / 4) / 256, 256, 0, stream>>>(feat, featbf);
    wtrans_kernel<<<64, 256, 0, stream>>>(W1, W2, w1t, w2t);
    bin_kernel<<<(N_EDGES + EPB - 1) / EPB, 256, 0, stream>>>(src, dst, bincnt, binpair);
    csr_kernel<<<NBINS, 256, 0, stream>>>(bincnt, binpair, rowptr, csr);
    gather_kernel<<<NPAD / 4, 256, 0, stream>>>(featbf, rowptr, csr, eps, hbf);
    mlp_kernel<<<1563, 256, 0, stream>>>((const short*)hbf, w1t, w2t, b1, b2, out);
}

// Round 4
// 374.711 us; speedup vs baseline: 1.5307x; 1.0289x over previous
//
#include <hip/hip_runtime.h>
#include <stdint.h>

#define N_NODES 100000
#define N_EDGES 3200000
#define DIM 128
#define NPAD 100032   // 1563 * 64
#define NBINS 391     // ceil(100000 / 256) -- 256 nodes per bin
#define BCAP 10240    // bin capacity; mean 8192
#define EPB 4096      // edges per bin_kernel block (16/thread)

typedef short short8 __attribute__((ext_vector_type(8)));
typedef float f32x4 __attribute__((ext_vector_type(4)));

__device__ __forceinline__ short f2bf(float x) {
    uint32_t u = __builtin_bit_cast(uint32_t, x);
    u += 0x7fffu + ((u >> 16) & 1u);   // round-to-nearest-even
    return (short)(u >> 16);
}
__device__ __forceinline__ float bflo(uint32_t p) {
    return __builtin_bit_cast(float, p << 16);
}
__device__ __forceinline__ float bfhi(uint32_t p) {
    return __builtin_bit_cast(float, p & 0xffff0000u);
}
__device__ __forceinline__ uint32_t pack2(float x, float y) {
    return (uint32_t)(uint16_t)f2bf(x) | ((uint32_t)(uint16_t)f2bf(y) << 16);
}

// ---- K1: fused prep: feat->bf16 cast, W transpose, bincnt zero ----------
__global__ __launch_bounds__(256) void prep_kernel(const float* __restrict__ feat,
                                                   uint32_t* __restrict__ featbf,
                                                   const float* __restrict__ w1,
                                                   const float* __restrict__ w2,
                                                   short* __restrict__ w1t,
                                                   short* __restrict__ w2t,
                                                   int* __restrict__ bincnt) {
    int b = blockIdx.x, t = threadIdx.x;
    if (b < 12500) {                       // cast: 3.2M float4s
        int i = b * 256 + t;
        float4 f = ((const float4*)feat)[i];
        featbf[2 * i]     = pack2(f.x, f.y);
        featbf[2 * i + 1] = pack2(f.z, f.w);
    } else if (b < 12564) {                // weight transpose: 16384 elems
        int i = (b - 12500) * 256 + t;
        int k = i >> 7, n = i & 127;
        w1t[n * DIM + k] = f2bf(w1[i]);
        w2t[n * DIM + k] = f2bf(w2[i]);
    } else {                               // zero bincnt (512 ints over 2 blocks)
        int i = (b - 12564) * 256 + t;
        bincnt[i] = 0;
    }
}

// ---- K3a: bin edges by dst>>8, LDS counting-sort, coalesced write-out ---
__global__ __launch_bounds__(256) void bin_kernel(const int* __restrict__ src,
                                                  const int* __restrict__ dst,
                                                  int* __restrict__ bincnt,
                                                  uint32_t* __restrict__ binpair) {
    __shared__ int hist[512];
    __shared__ int scanv[512];
    __shared__ int scan256[256];
    __shared__ int gbase[NBINS];
    __shared__ int cursor[NBINS];
    __shared__ uint32_t sorted[EPB];
    __shared__ int saddr[EPB];
    int t = threadIdx.x;
    for (int i = t; i < 512; i += 256) hist[i] = 0;
    __syncthreads();
    int e0 = blockIdx.x * EPB;
    int nn = min(EPB, N_EDGES - e0);
    int d[16];
#pragma unroll
    for (int i = 0; i < 16; i++) {
        int idx = i * 256 + t;
        d[i] = (idx < nn) ? dst[e0 + idx] : -1;
        if (d[i] >= 0) atomicAdd(&hist[d[i] >> 8], 1);
    }
    __syncthreads();
    int h0 = hist[2 * t], h1 = hist[2 * t + 1];
    scan256[t] = h0 + h1;
    __syncthreads();
    for (int dd = 1; dd < 256; dd <<= 1) {
        int v = (t >= dd) ? scan256[t - dd] : 0;
        __syncthreads();
        scan256[t] += v;
        __syncthreads();
    }
    int pairExcl = scan256[t] - (h0 + h1);
    scanv[2 * t] = pairExcl;
    scanv[2 * t + 1] = pairExcl + h0;
    for (int b = t; b < NBINS; b += 256) {
        int h = hist[b];
        gbase[b] = h ? atomicAdd(&bincnt[b], h) : 0;
        cursor[b] = 0;
    }
    __syncthreads();
#pragma unroll
    for (int i = 0; i < 16; i++) {
        if (d[i] >= 0) {
            int b = d[i] >> 8;
            int slot = atomicAdd(&cursor[b], 1);
            int p = scanv[b] + slot;
            int g = gbase[b] + slot;
            int e = e0 + i * 256 + t;
            sorted[p] = (uint32_t)src[e] | ((uint32_t)(d[i] & 255) << 24);
            saddr[p] = (g < BCAP) ? (b * BCAP + g) : -1;
        }
    }
    __syncthreads();
    for (int i = t; i < nn; i += 256) {
        int a = saddr[i];
        if (a >= 0) binpair[a] = sorted[i];
    }
}

// ---- K3b: per-bin counting sort -> CSR ----------------------------------
__global__ __launch_bounds__(256) void csr_kernel(const int* __restrict__ bincnt,
                                                  const uint32_t* __restrict__ binpair,
                                                  int* __restrict__ rowptr,
                                                  int* __restrict__ csr) {
    __shared__ int hist[256];
    __shared__ int cursor[256];
    __shared__ int sc[256];
    __shared__ int binbase_s;
    int b = blockIdx.x;
    int t = threadIdx.x;
    int partial = 0;
    for (int j = t; j < b; j += 256) partial += min(bincnt[j], BCAP);
    sc[t] = partial;
    __syncthreads();
    for (int dd = 128; dd > 0; dd >>= 1) {
        if (t < dd) sc[t] += sc[t + dd];
        __syncthreads();
    }
    if (t == 0) binbase_s = sc[0];
    hist[t] = 0;
    __syncthreads();
    int binbase = binbase_s;
    int cntb = min(bincnt[b], BCAP);
    const uint32_t* pairs = binpair + (size_t)b * BCAP;
    for (int i = t; i < cntb; i += 256)
        atomicAdd(&hist[pairs[i] >> 24], 1);
    __syncthreads();
    int val = hist[t];
    sc[t] = val;
    __syncthreads();
    for (int dd = 1; dd < 256; dd <<= 1) {
        int addv = (t >= dd) ? sc[t - dd] : 0;
        __syncthreads();
        sc[t] += addv;
        __syncthreads();
    }
    int excl = sc[t] - val;
    rowptr[(b << 8) + t] = binbase + excl;
    cursor[t] = excl;
    __syncthreads();
    for (int i = t; i < cntb; i += 256) {
        uint32_t p = pairs[i];
        int s2 = atomicAdd(&cursor[p >> 24], 1);
        csr[binbase + s2] = (int)(p & 0x00FFFFFFu);
    }
}

#define ACC8(q) do { \
    a0 += bflo((q).x); a1 += bfhi((q).x); a2 += bflo((q).y); a3 += bfhi((q).y); \
    a4 += bflo((q).z); a5 += bfhi((q).z); a6 += bflo((q).w); a7 += bfhi((q).w); } while (0)

// ---- K4: wave-per-node gather; dwordx4 = 4 rows/instr, 8 loads in flight
__global__ __launch_bounds__(256) void gather_kernel(const uint32_t* __restrict__ featbf,
                                                     const int* __restrict__ rowptr,
                                                     const int* __restrict__ csr,
                                                     const float* __restrict__ eps,
                                                     uint32_t* __restrict__ hbf) {
    int wid = blockIdx.x * 4 + (threadIdx.x >> 6);
    int lane = threadIdx.x & 63;
    int quarter = lane >> 4;    // which of 4 edges in a load group
    int col = lane & 15;        // uint4 column: 16 lanes x 16B = 256B row
    if (wid >= N_NODES) {
        if (wid < NPAD) hbf[wid * 64 + lane] = 0;
        return;
    }
    float e1 = 1.0f + eps[0];
    uint4 sf = *(const uint4*)&featbf[wid * 64 + col * 4];  // self row (early)
    float a0 = 0.f, a1 = 0.f, a2 = 0.f, a3 = 0.f;
    float a4 = 0.f, a5 = 0.f, a6 = 0.f, a7 = 0.f;
    int start = rowptr[wid], end = rowptr[wid + 1];
    for (int base = start; base < end; base += 64) {
        int m = min(64, end - base);
        int u = (lane < m) ? csr[base + lane] : 0;
        int j = 0;
        for (; j + 32 <= m; j += 32) {   // full 32-edge burst: 8 KB in flight
            int i0 = __shfl(u, j + quarter);
            int i1 = __shfl(u, j + 4 + quarter);
            int i2 = __shfl(u, j + 8 + quarter);
            int i3 = __shfl(u, j + 12 + quarter);
            int i4 = __shfl(u, j + 16 + quarter);
            int i5 = __shfl(u, j + 20 + quarter);
            int i6 = __shfl(u, j + 24 + quarter);
            int i7 = __shfl(u, j + 28 + quarter);
            uint4 q0 = *(const uint4*)&featbf[i0 * 64 + col * 4];
            uint4 q1 = *(const uint4*)&featbf[i1 * 64 + col * 4];
            uint4 q2 = *(const uint4*)&featbf[i2 * 64 + col * 4];
            uint4 q3 = *(const uint4*)&featbf[i3 * 64 + col * 4];
            uint4 q4 = *(const uint4*)&featbf[i4 * 64 + col * 4];
            uint4 q5 = *(const uint4*)&featbf[i5 * 64 + col * 4];
            uint4 q6 = *(const uint4*)&featbf[i6 * 64 + col * 4];
            uint4 q7 = *(const uint4*)&featbf[i7 * 64 + col * 4];
            ACC8(q0); ACC8(q1); ACC8(q2); ACC8(q3);
            ACC8(q4); ACC8(q5); ACC8(q6); ACC8(q7);
        }
        if (j < m) {                     // masked tail burst (1..31 edges)
            int mm = m - 1;
            int p0 = j + quarter,      p1 = j + 4 + quarter;
            int p2 = j + 8 + quarter,  p3 = j + 12 + quarter;
            int p4 = j + 16 + quarter, p5 = j + 20 + quarter;
            int p6 = j + 24 + quarter, p7 = j + 28 + quarter;
            int i0 = __shfl(u, min(p0, mm)), i1 = __shfl(u, min(p1, mm));
            int i2 = __shfl(u, min(p2, mm)), i3 = __shfl(u, min(p3, mm));
            int i4 = __shfl(u, min(p4, mm)), i5 = __shfl(u, min(p5, mm));
            int i6 = __shfl(u, min(p6, mm)), i7 = __shfl(u, min(p7, mm));
            uint4 q0 = *(const uint4*)&featbf[i0 * 64 + col * 4];
            uint4 q1 = *(const uint4*)&featbf[i1 * 64 + col * 4];
            uint4 q2 = *(const uint4*)&featbf[i2 * 64 + col * 4];
            uint4 q3 = *(const uint4*)&featbf[i3 * 64 + col * 4];
            uint4 q4 = *(const uint4*)&featbf[i4 * 64 + col * 4];
            uint4 q5 = *(const uint4*)&featbf[i5 * 64 + col * 4];
            uint4 q6 = *(const uint4*)&featbf[i6 * 64 + col * 4];
            uint4 q7 = *(const uint4*)&featbf[i7 * 64 + col * 4];
            if (p0 < m) ACC8(q0);
            if (p1 < m) ACC8(q1);
            if (p2 < m) ACC8(q2);
            if (p3 < m) ACC8(q3);
            if (p4 < m) ACC8(q4);
            if (p5 < m) ACC8(q5);
            if (p6 < m) ACC8(q6);
            if (p7 < m) ACC8(q7);
        }
    }
    // reduce across the 4 quarters
    a0 += __shfl_xor(a0, 16); a1 += __shfl_xor(a1, 16);
    a2 += __shfl_xor(a2, 16); a3 += __shfl_xor(a3, 16);
    a4 += __shfl_xor(a4, 16); a5 += __shfl_xor(a5, 16);
    a6 += __shfl_xor(a6, 16); a7 += __shfl_xor(a7, 16);
    a0 += __shfl_xor(a0, 32); a1 += __shfl_xor(a1, 32);
    a2 += __shfl_xor(a2, 32); a3 += __shfl_xor(a3, 32);
    a4 += __shfl_xor(a4, 32); a5 += __shfl_xor(a5, 32);
    a6 += __shfl_xor(a6, 32); a7 += __shfl_xor(a7, 32);
    if (quarter == 0) {
        a0 += e1 * bflo(sf.x); a1 += e1 * bfhi(sf.x);
        a2 += e1 * bflo(sf.y); a3 += e1 * bfhi(sf.y);
        a4 += e1 * bflo(sf.z); a5 += e1 * bfhi(sf.z);
        a6 += e1 * bflo(sf.w); a7 += e1 * bfhi(sf.w);
        uint4 w;
        w.x = pack2(a0, a1); w.y = pack2(a2, a3);
        w.z = pack2(a4, a5); w.w = pack2(a6, a7);
        *(uint4*)&hbf[wid * 64 + col * 4] = w;
    }
}

// ---- K5: fused 2-layer MLP via bf16 MFMA 16x16x32 -----------------------
__global__ __launch_bounds__(256) void mlp_kernel(const short* __restrict__ hbf,
                                                  const short* __restrict__ w1t,
                                                  const short* __restrict__ w2t,
                                                  const float* __restrict__ b1,
                                                  const float* __restrict__ b2,
                                                  float* __restrict__ out) {
    __shared__ __align__(16) short h1s[4][16 * 136];
    const int wave = threadIdx.x >> 6;
    const int lane = threadIdx.x & 63;
    const int l15 = lane & 15;
    const int quad = lane >> 4;

    float b1v[8], b2v[8];
#pragma unroll
    for (int n = 0; n < 8; n++) {
        b1v[n] = b1[n * 16 + l15];
        b2v[n] = b2[n * 16 + l15];
    }

    const int ntiles = NPAD / 64;
    for (int tile = blockIdx.x; tile < ntiles; tile += gridDim.x) {
        int row0 = tile * 64 + wave * 16;
        f32x4 acc[8];
#pragma unroll
        for (int n = 0; n < 8; n++) acc[n] = (f32x4){0.f, 0.f, 0.f, 0.f};
#pragma unroll
        for (int kb = 0; kb < DIM; kb += 32) {
            short8 a = *(const short8*)&hbf[(row0 + l15) * DIM + kb + quad * 8];
#pragma unroll
            for (int n = 0; n < 8; n++) {
                short8 b = *(const short8*)&w1t[(n * 16 + l15) * DIM + kb + quad * 8];
                acc[n] = __builtin_amdgcn_mfma_f32_16x16x32_bf16(a, b, acc[n], 0, 0, 0);
            }
        }
#pragma unroll
        for (int n = 0; n < 8; n++) {
#pragma unroll
            for (int r = 0; r < 4; r++) {
                float v = acc[n][r] + b1v[n];
                v = v > 0.f ? v : 0.f;
                h1s[wave][(quad * 4 + r) * 136 + n * 16 + l15] = f2bf(v);
            }
        }
        __syncthreads();
        f32x4 acc2[8];
#pragma unroll
        for (int n = 0; n < 8; n++) acc2[n] = (f32x4){0.f, 0.f, 0.f, 0.f};
#pragma unroll
        for (int kb = 0; kb < DIM; kb += 32) {
            short8 a2 = *(const short8*)&h1s[wave][l15 * 136 + kb + quad * 8];
#pragma unroll
            for (int n = 0; n < 8; n++) {
                short8 b = *(const short8*)&w2t[(n * 16 + l15) * DIM + kb + quad * 8];
                acc2[n] = __builtin_amdgcn_mfma_f32_16x16x32_bf16(a2, b, acc2[n], 0, 0, 0);
            }
        }
#pragma unroll
        for (int n = 0; n < 8; n++) {
#pragma unroll
            for (int r = 0; r < 4; r++) {
                int row = row0 + quad * 4 + r;
                if (row < N_NODES)
                    out[row * DIM + n * 16 + l15] = acc2[n][r] + b2v[n];
            }
        }
        __syncthreads();
    }
}

extern "C" void kernel_launch(void* const* d_in, const int* in_sizes, int n_in,
                              void* d_out, int out_size, void* d_ws, size_t ws_size,
                              hipStream_t stream) {
    const float* feat = (const float*)d_in[0];
    const int* src    = (const int*)d_in[1];
    const int* dst    = (const int*)d_in[2];
    const float* eps  = (const float*)d_in[3];
    const float* W1   = (const float*)d_in[4];
    const float* b1   = (const float*)d_in[5];
    const float* W2   = (const float*)d_in[6];
    const float* b2   = (const float*)d_in[7];
    float* out = (float*)d_out;

    char* ws = (char*)d_ws;
    int*      bincnt  = (int*)ws;                          //         2,048 B
    int*      rowptr  = (int*)(ws + 2048);                 //       401,408 B
    int*      csr     = (int*)(ws + 403456);               //    12,800,000 B
    uint32_t* binpair = (uint32_t*)(ws + 13203456);        //    16,015,360 B
    uint32_t* featbf  = (uint32_t*)(ws + 29218816);        //    25,600,000 B
    uint32_t* hbf     = (uint32_t*)(ws + 54818816);        //    25,608,192 B
    short*    w1t     = (short*)(ws + 80427008);           //        32,768 B
    short*    w2t     = (short*)(ws + 80459776);           // ends 80,492,544 B

    prep_kernel<<<12566, 256, 0, stream>>>(feat, featbf, W1, W2, w1t, w2t, bincnt);
    bin_kernel<<<(N_EDGES + EPB - 1) / EPB, 256, 0, stream>>>(src, dst, bincnt, binpair);
    csr_kernel<<<NBINS, 256, 0, stream>>>(bincnt, binpair, rowptr, csr);
    gather_kernel<<<NPAD / 4, 256, 0, stream>>>(featbf, rowptr, csr, eps, hbf);
    mlp_kernel<<<1563, 256, 0, stream>>>((const short*)hbf, w1t, w2t, b1, b2, out);
}